// Round 14
// baseline (206.608 us; speedup 1.0000x reference)
//
#include <hip/hip_runtime.h>
#include <hip/hip_bf16.h>

#define NROWS 65537
#define NFR   65536
#define EDIM  256

typedef __bf16 bf16x8 __attribute__((ext_vector_type(8)));
typedef __bf16 bf16x4 __attribute__((ext_vector_type(4)));
typedef float  f32x4  __attribute__((ext_vector_type(4)));

#define INV_SQRT_HD 0.17677669529663687f  // 1/sqrt(32)

__device__ __forceinline__ float wsum64(float v){
#pragma unroll
  for (int m = 1; m < 64; m <<= 1) v += __shfl_xor(v, m);
  return v;
}
__device__ __forceinline__ float wmax64(float v){
#pragma unroll
  for (int m = 1; m < 64; m <<= 1) v = fmaxf(v, __shfl_xor(v, m));
  return v;
}

// async global->LDS, 16B per lane; LDS dest is wave-uniform base + lane*16 (HW-added)
__device__ __forceinline__ void gload_lds16(const void* g, void* l){
  __builtin_amdgcn_global_load_lds(
      (const __attribute__((address_space(1))) void*)g,
      (__attribute__((address_space(3))) void*)l, 16, 0, 0);
}

// ---------- fused prep: weight sums + MFMA-fragment packing + phase-1 token LN ----------
__global__ __launch_bounds__(256) void k_prep(
    const float* __restrict__ wqt, const float* __restrict__ wkt, const float* __restrict__ wvt,
    const float* __restrict__ wqs, const float* __restrict__ wks, const float* __restrict__ wvs,
    const float* __restrict__ wt_t, const float* __restrict__ wt_s, const float* __restrict__ wmlp_f,
    const float* __restrict__ emb, const float* __restrict__ ltg, const float* __restrict__ ltb,
    float* __restrict__ sums, float* __restrict__ that1raw,
    float* __restrict__ y0f, __bf16* __restrict__ y0bf, float* __restrict__ tokacc,
    __bf16* __restrict__ pT, __bf16* __restrict__ pS, __bf16* __restrict__ pM){
  const int tid = threadIdx.x;
  if (blockIdx.x == 102){               // token row LN_t (one wave; no SUMS dependency)
    if (tid >= 64) return;
    const int l = tid;
    int c0 = l*4;
    const float4 xv = *(const float4*)(emb + c0);
    float mean = wsum64(xv.x+xv.y+xv.z+xv.w) * (1.f/256.f);
    float d0=xv.x-mean, d1=xv.y-mean, d2=xv.z-mean, d3=xv.w-mean;
    float rstd = rsqrtf(wsum64(d0*d0+d1*d1+d2*d2+d3*d3)*(1.f/256.f) + 1e-5f);
    const float4 gv = *(const float4*)(ltg + c0);
    const float4 bv = *(const float4*)(ltb + c0);
    float y0 = d0*rstd*gv.x+bv.x, y1 = d1*rstd*gv.y+bv.y;
    float y2 = d2*rstd*gv.z+bv.z, y3 = d3*rstd*gv.w+bv.w;
    float hs = y0*y0+y1*y1+y2*y2+y3*y3;
    hs += __shfl_xor(hs,1); hs += __shfl_xor(hs,2); hs += __shfl_xor(hs,4);
    if ((l & 7) == 0) that1raw[l>>3] = hs;          // RAW (c1 applied in k_score)
    y0f[c0+0]=y0; y0f[c0+1]=y1; y0f[c0+2]=y2; y0f[c0+3]=y3;
    y0bf[c0+0]=(__bf16)y0; y0bf[c0+1]=(__bf16)y1; y0bf[c0+2]=(__bf16)y2; y0bf[c0+3]=(__bf16)y3;
    tokacc[c0+0]=0.f; tokacc[c0+1]=0.f; tokacc[c0+2]=0.f; tokacc[c0+3]=0.f;
    return;
  }
  if (blockIdx.x < 6){
    const float* arr[6] = {wqt,wkt,wvt,wqs,wks,wvs};
    const float* p = arr[blockIdx.x];
    float s = 0.f;
#pragma unroll
    for (int k = 0; k < 8; k++){
      float4 v = *(const float4*)(p + (tid + k*256)*4);
      s += v.x+v.y+v.z+v.w;
    }
    s = wsum64(s);
    __shared__ float red[4];
    if ((tid & 63) == 0) red[tid>>6] = s;
    __syncthreads();
    if (tid == 0) sums[blockIdx.x] = red[0]+red[1]+red[2]+red[3];
    return;
  }
  int t = (blockIdx.x-6)*256 + tid;   // 96*256 = 3*8192 fragments
  int m = t >> 13, fi = t & 8191;
  int l = fi & 63, ct = (fi>>6)&15, kk = fi>>10;
  int n  = ct*16 + (l&15);
  int kb = kk*32 + ((l>>4)<<3);
  if (m == 0){
#pragma unroll
    for (int j=0;j<8;j++) pT[(size_t)fi*8+j] = (__bf16)wt_t[(kb+j)*256 + n];
  } else if (m == 1){
#pragma unroll
    for (int j=0;j<8;j++) pS[(size_t)fi*8+j] = (__bf16)wt_s[(kb+j)*256 + n];
  } else {
#pragma unroll
    for (int j=0;j<8;j++) pM[(size_t)fi*8+j] = (__bf16)wmlp_f[n*256 + kb + j];
  }
}

// ---------- phase-1 frames: LN -> mr0 + IN-BLOCK group softmax -> awsv/aw0 + pgrp partials ----------
__global__ __launch_bounds__(256) void k_score(
    const float* __restrict__ x, const float* __restrict__ g, const float* __restrict__ b,
    const float* __restrict__ S, int si,
    const float* __restrict__ that1raw,
    float* __restrict__ awsv, float* __restrict__ aw0sv,
    float* __restrict__ pgrp, float* __restrict__ mr0){
  const float c1 = S[3*si]*S[3*si+1]*INV_SQRT_HD;
  const int tid = threadIdx.x, w = tid>>6, l = tid&63;
  const int lq = l&15, q = l>>4;

  __shared__ float sLds[8][64];
  __shared__ float gsLds[4][256];
  const int chunk = blockIdx.x;          // 1024 blocks x 64 frames == softmax groups
  float4 gvv[4], bvv[4];
#pragma unroll
  for (int p=0;p<4;p++){
    gvv[p] = *(const float4*)(g + p*64 + lq*4);
    bvv[p] = *(const float4*)(b + p*64 + lq*4);
  }
  float gs[4][4];
#pragma unroll
  for (int p=0;p<4;p++){ gs[p][0]=0.f; gs[p][1]=0.f; gs[p][2]=0.f; gs[p][3]=0.f; }

#pragma unroll
  for (int it=0; it<4; it++){
    const int fo = w*16 + it*4 + q;     // frame within chunk
    const size_t grow = (size_t)(1 + chunk*64 + fo);
    float4 v[4];
#pragma unroll
    for (int p=0;p<4;p++) v[p] = *(const float4*)(x + grow*256 + p*64 + lq*4);
    float s = 0.f;
#pragma unroll
    for (int p=0;p<4;p++) s += v[p].x+v[p].y+v[p].z+v[p].w;
    s += __shfl_xor(s,1); s += __shfl_xor(s,2); s += __shfl_xor(s,4); s += __shfl_xor(s,8);
    const float mean = s * (1.f/256.f);
    float ss = 0.f;
#pragma unroll
    for (int p=0;p<4;p++){
      float a0=v[p].x-mean,a1=v[p].y-mean,a2=v[p].z-mean,a3=v[p].w-mean;
      ss += a0*a0+a1*a1+a2*a2+a3*a3;
    }
    ss += __shfl_xor(ss,1); ss += __shfl_xor(ss,2); ss += __shfl_xor(ss,4); ss += __shfl_xor(ss,8);
    const float rstd = rsqrtf(ss*(1.f/256.f) + 1e-5f);
    if (lq == 0){ mr0[grow*2+0] = mean; mr0[grow*2+1] = rstd; }
    float hs[4];
#pragma unroll
    for (int p=0;p<4;p++){
      float y0=(v[p].x-mean)*rstd*gvv[p].x+bvv[p].x;
      float y1=(v[p].y-mean)*rstd*gvv[p].y+bvv[p].y;
      float y2=(v[p].z-mean)*rstd*gvv[p].z+bvv[p].z;
      float y3=(v[p].w-mean)*rstd*gvv[p].w+bvv[p].w;
      gs[p][0]+=y0; gs[p][1]+=y1; gs[p][2]+=y2; gs[p][3]+=y3;
      hs[p] = y0*y0+y1*y1+y2*y2+y3*y3;
    }
#pragma unroll
    for (int p=0;p<4;p++){
      hs[p] += __shfl_xor(hs[p],1); hs[p] += __shfl_xor(hs[p],2); hs[p] += __shfl_xor(hs[p],4);
    }
    if ((lq & 7) == 0){
#pragma unroll
      for (int p=0;p<4;p++) sLds[2*p + (lq>>3)][fo] = c1*hs[p];
    }
  }
#pragma unroll
  for (int p=0;p<4;p++)
#pragma unroll
    for (int j=0;j<4;j++){
      gs[p][j] += __shfl_xor(gs[p][j], 16);
      gs[p][j] += __shfl_xor(gs[p][j], 32);
    }
  if (q == 0){
#pragma unroll
    for (int p=0;p<4;p++)
#pragma unroll
      for (int j=0;j<4;j++) gsLds[w][p*64 + lq*4 + j] = gs[p][j];
  }
  __syncthreads();

  // ---- in-block group softmax: wave w handles heads 2w, 2w+1 ----
#pragma unroll
  for (int hh=0; hh<2; hh++){
    const int h = w*2 + hh;
    float v = sLds[h][l];
    float tv = c1 * that1raw[h];
    float m = fmaxf(wmax64(v), tv);
    float e = __expf(v - m);
    float se = wsum64(e);
    float te = __expf(tv - m);
    float inv = S[3*si+2] / (se + te);
    awsv[h*NFR + chunk*64 + l] = e*inv;
    if (l == 0) aw0sv[(h<<10) + chunk] = te*inv;
  }

  // ---- per-chunk column-sum partials (reduced by k_tok1; no atomic storm) ----
  pgrp[chunk*256 + tid] = gsLds[0][tid]+gsLds[1][tid]+gsLds[2][tid]+gsLds[3][tid];
}

// ---------- group softmax (phase-2 only) -> per-row aw*sv planes + per-group aw0*sv ----------
template<int REPS>
__global__ __launch_bounds__(256) void k_softmax(
    const float* __restrict__ splane, const float* __restrict__ that,
    const float* __restrict__ S, int si,
    float* __restrict__ awsv, float* __restrict__ aw0sv, int nwaves){
  const int w = threadIdx.x>>6, l = threadIdx.x&63;
  const int gw = blockIdx.x*4 + w;
  if (gw >= nwaves) return;
  const int h = gw & 7, a = gw >> 3;
  const int base = a*(REPS*64);
  const float tv = that[h];
  float vals[REPS];
  float m = tv;
#pragma unroll
  for (int j = 0; j < REPS; j++){ vals[j] = splane[h*NFR + base + j*64 + l]; m = fmaxf(m, vals[j]); }
  m = wmax64(m);
  float se = 0.f;
#pragma unroll
  for (int j = 0; j < REPS; j++){ vals[j] = __expf(vals[j]-m); se += vals[j]; }
  se = wsum64(se);
  const float te = __expf(tv - m);
  const float inv = S[3*si+2] / (se + te);
#pragma unroll
  for (int j = 0; j < REPS; j++) awsv[h*NFR + base + j*64 + l] = vals[j]*inv;
  if (l == 0) aw0sv[(h<<10) + a] = te*inv;
}

// ---------- weighted reduce of partial group sums into the tok accumulator (phase 1 only) ----------
__global__ void k_tok1(const float* __restrict__ pgrp, const float* __restrict__ aw0sv,
                       float* __restrict__ tokacc, int cshift){
  const int c = threadIdx.x, h = c>>5;
  float acc = 0.f;
  const int cbase = blockIdx.x*32;      // 32 blocks x 32 chunks
  for (int k = 0; k < 32; k++){
    int chunk = cbase + k;
    acc += aw0sv[(h<<10) + (chunk>>cshift)] * pgrp[chunk*256 + c];
  }
  atomicAdd(&tokacc[c], acc);
}

// ---------- fused attn GEMM with LN-epilogue (phase 1 only; round-9 proven) ----------
template<int PH>
__global__ __launch_bounds__(256,3) void k_gemmF(
    const float* __restrict__ xf, const __bf16* __restrict__ xb,
    __bf16* __restrict__ outb,
    const __bf16* __restrict__ Bp, const float* __restrict__ mrA,
    const float* __restrict__ gA, const float* __restrict__ bA,
    const __bf16* __restrict__ y0bf_in,
    const float* __restrict__ awsv, const float* __restrict__ aw0sv, int d1shift,
    const float* __restrict__ S, int si,
    const float* __restrict__ Wt_f32, const float* __restrict__ y0f_in,
    const float* __restrict__ tokacc_in,
    const float* __restrict__ g2, const float* __restrict__ b2,
    float* __restrict__ mrOut,
    float* __restrict__ that_out, float* __restrict__ y0f_out,
    __bf16* __restrict__ y0bf_out, float* __restrict__ tokacc_out,
    float* __restrict__ splane, float* __restrict__ pgrp)
{
  const int tid = threadIdx.x, w = tid>>6, l = tid&63;
  const int lq = l&15, q = l>>4;

  __shared__ char smem[49152];                 // 3x16KB B bufs during MFMA; tile+sH+gsL after
  __shared__ float mr[4][8][2];
  __bf16* bsh = (__bf16*)smem;
  float* sH  = (float*)(smem + 32768);         // [8][64], PH1 only (3rd buf, dead post-loop)
  float* gsL = (float*)(smem + 32768 + 2048);  // [4][256], PH1 only

  if (blockIdx.x == 1024){   // token row (aliases onto smem/mr)
    float* tok  = (float*)smem;                  // 256 f32
    float* yy   = (float*)(smem + 1024);         // 256 f32
    float* red  = &mr[0][0][0];                  // 4 f32
    float* red2 = &mr[1][0][0];                  // 4 f32
    tok[tid] = S[3*si+2]*y0f_in[tid] + tokacc_in[tid];
    __syncthreads();
    float s = 0.f;
    for (int c = 0; c < 256; c++) s += tok[c]*Wt_f32[c*256 + tid];
    float pv = s + ((PH==1) ? xf[tid] : (float)xb[tid]);   // new row-0 value
    outb[tid] = (__bf16)pv;
    float sw = wsum64(pv);
    if (l == 0) red[w] = sw;
    __syncthreads();
    float mean = (red[0]+red[1]+red[2]+red[3]) * (1.f/256.f);
    float d = pv - mean;
    float dv = wsum64(d*d);
    if (l == 0) red2[w] = dv;
    __syncthreads();
    float rstd = rsqrtf((red2[0]+red2[1]+red2[2]+red2[3])*(1.f/256.f) + 1e-5f);
    if (PH == 1){
      float yv = d*rstd*g2[tid] + b2[tid];
      yy[tid] = yv*yv;
      y0f_out[tid] = yv;
      y0bf_out[tid] = (__bf16)yv;
      tokacc_out[tid] = 0.f;
      __syncthreads();
      if (tid < 8){
        float hsum = 0.f;
        for (int c = 0; c < 32; c++) hsum += yy[tid*32 + c];
        const float c1n = S[3*(si+1)]*S[3*(si+1)+1]*INV_SQRT_HD;
        that_out[tid] = c1n*hsum;
      }
    } else {
      if (tid == 0){ mrOut[0] = mean; mrOut[1] = rstd; }
    }
    return;
  }

  const int rbase = blockIdx.x*64 + w*16;        // frame base of this wave
  const size_t ar = (size_t)(1 + rbase + lq);
  const float mean_a = mrA[ar*2+0];
  const float rstd_a = mrA[ar*2+1];
  const int fr = rbase + lq;

  // ---- prologue: stage B[0]->buf0 and B[1]->buf1; wave w covers 4 x 1KB slices each ----
#pragma unroll
  for (int i=0;i<4;i++)
    gload_lds16(Bp + (((i<<2)+w)<<9) + l*8, bsh + (((i<<2)+w)<<9));
#pragma unroll
  for (int i=0;i<4;i++)
    gload_lds16(Bp + 8192 + (((i<<2)+w)<<9) + l*8, bsh + 8192 + (((i<<2)+w)<<9));

  // ---- hoisted A-side: build all 8 av fragments before the kk loop ----
  bf16x8 av[8];
#pragma unroll
  for (int kk=0;kk<8;kk++){
    const int co = kk*32 + q*8;
    float va[8];
    if (PH==1){
      f32x4 u0 = *(const f32x4*)(xf + ar*256 + co);
      f32x4 u1 = *(const f32x4*)(xf + ar*256 + co + 4);
#pragma unroll
      for (int j=0;j<4;j++){ va[j]=u0[j]; va[4+j]=u1[j]; }
    } else {
      bf16x8 u = *(const bf16x8*)(xb + ar*256 + co);
#pragma unroll
      for (int j=0;j<8;j++) va[j]=(float)u[j];
    }
    f32x4 ga0 = *(const f32x4*)(gA + co), ga1 = *(const f32x4*)(gA + co + 4);
    f32x4 ba0 = *(const f32x4*)(bA + co), ba1 = *(const f32x4*)(bA + co + 4);
    bf16x8 y0v = *(const bf16x8*)(y0bf_in + co);
    const float A  = awsv[kk*NFR + fr];
    const float A0 = aw0sv[(kk<<10) + (fr>>d1shift)];
#pragma unroll
    for (int j=0;j<4;j++){
      float yv = (va[j]-mean_a)*rstd_a*ga0[j] + ba0[j];
      av[kk][j] = (__bf16)(A*yv + A0*(float)y0v[j]);
    }
#pragma unroll
    for (int j=0;j<4;j++){
      float yv = (va[4+j]-mean_a)*rstd_a*ga1[j] + ba1[j];
      av[kk][4+j] = (__bf16)(A*yv + A0*(float)y0v[4+j]);
    }
  }

  // ---- drain prologue completely: loop-entry outstanding VMEM = 0 for every wave ----
  __syncthreads();

  // ---- MFMA loop: counted vmcnt, fused wait+barrier asm, sched fences both sides ----
  f32x4 acc[16];
  const f32x4 zero = {0.f,0.f,0.f,0.f};
#pragma unroll
  for (int ct=0;ct<16;ct++) acc[ct]=zero;
#pragma unroll
  for (int kk=0;kk<8;kk++){
    __builtin_amdgcn_sched_barrier(0);
    if (kk<7) asm volatile("s_waitcnt vmcnt(4)\n\ts_barrier" ::: "memory");
    else      asm volatile("s_waitcnt vmcnt(0)\n\ts_barrier" ::: "memory");
    __builtin_amdgcn_sched_barrier(0);
    if (kk<6){
#pragma unroll
      for (int i=0;i<4;i++)
        gload_lds16(Bp + (size_t)(kk+2)*8192 + (((i<<2)+w)<<9) + l*8,
                    bsh + ((kk+2)%3)*8192 + (((i<<2)+w)<<9));
    }
#pragma unroll
    for (int ct=0;ct<16;ct++){
      bf16x8 bfv = *(const bf16x8*)(bsh + (kk%3)*8192 + (((ct<<6)+l)<<3));
      acc[ct] = __builtin_amdgcn_mfma_f32_16x16x32_bf16(av[kk], bfv, acc[ct], 0,0,0);
    }
  }
  __builtin_amdgcn_sched_barrier(0);
  __syncthreads();                  // all B reads done before smem is reused as the tile

  char* myl = smem + w*8192;
  const float4 gvc = *(const float4*)(g2 + l*4);
  const float4 bvc = *(const float4*)(b2 + l*4);
  float gs0=0.f, gs1=0.f, gs2=0.f, gs3=0.f;
  const float c1n = (PH==1) ? S[3*(si+1)]*S[3*(si+1)+1]*INV_SQRT_HD : 0.f;

#pragma unroll
  for (int h=0; h<2; h++){
    if (h) __syncthreads();
    if ((q>>1) == h){
      const int rl0 = (q&1)*4;
#pragma unroll
      for (int ct=0;ct<16;ct++){
#pragma unroll
        for (int rr=0;rr<4;rr++){
          int rl = rl0 + rr;
          unsigned byte = (unsigned)(rl*1024 + ct*64 + lq*4);
          *(float*)(myl + (byte ^ ((unsigned)(rl&7)<<4))) = acc[ct][rr];
        }
      }
    }
    __syncthreads();

#pragma unroll
    for (int i=0;i<8;i++){
      unsigned byte = (unsigned)(i*1024 + l*16);
      char* ap = myl + (byte ^ ((unsigned)(i&7)<<4));
      f32x4 cv = *(f32x4*)ap;
      const size_t grow = (size_t)(1 + rbase + h*8 + i);
      if (PH==1){
        const float4 xr = *(const float4*)(xf + grow*256 + l*4);
        cv[0]+=xr.x; cv[1]+=xr.y; cv[2]+=xr.z; cv[3]+=xr.w;
      } else {
        bf16x4 xr = *(const bf16x4*)(xb + grow*256 + l*4);
        cv[0]+=(float)xr[0]; cv[1]+=(float)xr[1]; cv[2]+=(float)xr[2]; cv[3]+=(float)xr[3];
      }
      *(f32x4*)ap = cv;
      bf16x4 ob; ob[0]=(__bf16)cv[0]; ob[1]=(__bf16)cv[1]; ob[2]=(__bf16)cv[2]; ob[3]=(__bf16)cv[3];
      *(bf16x4*)(outb + grow*256 + l*4) = ob;
    }

#pragma unroll
    for (int it=0; it<2; it++){
      int rl = it*4 + q;
      f32x4 v[4];
#pragma unroll
      for (int p=0;p<4;p++){
        unsigned byte = (unsigned)(rl*1024 + p*256 + lq*16);
        v[p] = *(f32x4*)(myl + (byte ^ ((unsigned)(rl&7)<<4)));
      }
      float s = 0.f;
#pragma unroll
      for (int p=0;p<4;p++) s += v[p][0]+v[p][1]+v[p][2]+v[p][3];
      s += __shfl_xor(s,1); s += __shfl_xor(s,2); s += __shfl_xor(s,4); s += __shfl_xor(s,8);
      float mean = s * (1.f/256.f);
      float ss = 0.f;
#pragma unroll
      for (int p=0;p<4;p++){
        float a0=v[p][0]-mean,a1=v[p][1]-mean,a2=v[p][2]-mean,a3=v[p][3]-mean;
        ss += a0*a0+a1*a1+a2*a2+a3*a3;
      }
      ss += __shfl_xor(ss,1); ss += __shfl_xor(ss,2); ss += __shfl_xor(ss,4); ss += __shfl_xor(ss,8);
      float rstd = rsqrtf(ss*(1.f/256.f) + 1e-5f);
      if (lq == 0){
        if (PH==1){ mr[w][rl][0] = mean; mr[w][rl][1] = rstd; }
        const size_t gr = (size_t)(1 + rbase + h*8 + rl);
        mrOut[gr*2+0] = mean; mrOut[gr*2+1] = rstd;
      }
    }

    if (PH==1){
#pragma unroll
      for (int i=0;i<8;i++){
        float mean = mr[w][i][0], rstd = mr[w][i][1];
        unsigned byte = (unsigned)(i*1024 + l*16);
        f32x4 cv = *(f32x4*)(myl + (byte ^ ((unsigned)(i&7)<<4)));
        float y0=(cv[0]-mean)*rstd*gvc.x+bvc.x;
        float y1=(cv[1]-mean)*rstd*gvc.y+bvc.y;
        float y2=(cv[2]-mean)*rstd*gvc.z+bvc.z;
        float y3=(cv[3]-mean)*rstd*gvc.w+bvc.w;
        gs0+=y0; gs1+=y1; gs2+=y2; gs3+=y3;
        float hp = y0*y0+y1*y1+y2*y2+y3*y3;
        hp += __shfl_xor(hp,1); hp += __shfl_xor(hp,2); hp += __shfl_xor(hp,4);
        if ((l & 7) == 0) sH[(l>>3)*64 + w*16 + h*8 + i] = c1n*hp;
      }
    }
  }

  if (PH==1){
    gsL[w*256 + l*4+0]=gs0; gsL[w*256 + l*4+1]=gs1; gsL[w*256 + l*4+2]=gs2; gsL[w*256 + l*4+3]=gs3;
    __syncthreads();
    pgrp[blockIdx.x*256 + tid] = gsL[0*256+tid]+gsL[1*256+tid]+gsL[2*256+tid]+gsL[3*256+tid];
#pragma unroll
    for (int rep = 0; rep < 2; rep++){
      int j = rep*256 + tid; int h = j>>6, fo = j&63;
      splane[h*NFR + blockIdx.x*64 + fo] = sH[h*64 + fo];
    }
  }
}

// ---------- fused phase-2 GEMM + final GEMM (round-11 proven) ----------
// Round-24: k_tok1(ph2) folded into the token block — it reduces PGRP (1024 chunks x 256,
// weighted by aw0sv ph2, cshift=4) inline (~1MB coalesced reads, hidden under the 1024
// sibling GEMM blocks). No race: PGRP written by gemmF1 (prior dispatch), read only here.
__global__ __launch_bounds__(256,2) void k_gemmFL(
    const __bf16* __restrict__ p1b,
    float* __restrict__ outf,
    const __bf16* __restrict__ Bp1,        // packed Wt_s
    const __bf16* __restrict__ Bp2,        // packed W_mlp
    const float* __restrict__ mrA,         // MR1
    const float* __restrict__ gA, const float* __restrict__ bA,   // ln_s
    const __bf16* __restrict__ y0bf_in,
    const float* __restrict__ awsv, const float* __restrict__ aw0sv, int d1shift,
    const float* __restrict__ S, int si,
    const float* __restrict__ Wt_f32,      // Wt_s (token)
    const float* __restrict__ y0f_in, const float* __restrict__ pgrp2,
    const float* __restrict__ g2, const float* __restrict__ b2,   // ln_m
    const float* __restrict__ wmlp, const float* __restrict__ bias)
{
  const int tid = threadIdx.x, w = tid>>6, l = tid&63;
  const int lq = l&15, q = l>>4;

  __shared__ char smem[81920];
  __bf16* bsh  = (__bf16*)smem;
  float*  mrS  = (float*)(smem + 32768);
  char*   tAw  = smem + 49152 + w*8192;    // this wave's bf16 p2 tile

  if (blockIdx.x == 1024){   // token row: tok-reduce + p2[0] + LN_m + final GEMM row 0
    float* tok  = (float*)smem;            // 256
    float* yy   = (float*)(smem + 1024);   // 256
    float* red  = (float*)(smem + 2048);   // 4
    float* red2 = (float*)(smem + 2064);   // 4
    // inline k_tok1(ph2): weighted reduce of 1024 chunk-partials (cshift=4)
    float acc0 = 0.f;
    {
      const int hh = tid>>5;
#pragma unroll 4
      for (int chunk = 0; chunk < 1024; chunk++)
        acc0 += aw0sv[(hh<<10) + (chunk>>4)] * pgrp2[chunk*256 + tid];
    }
    tok[tid] = S[3*si+2]*y0f_in[tid] + acc0;
    __syncthreads();
    float s = 0.f;
    for (int c = 0; c < 256; c++) s += tok[c]*Wt_f32[c*256 + tid];
    float pv = s + (float)p1b[tid];        // p2 row 0
    float sw = wsum64(pv);
    if (l == 0) red[w] = sw;
    __syncthreads();
    float mean = (red[0]+red[1]+red[2]+red[3]) * (1.f/256.f);
    float d = pv - mean;
    float dv = wsum64(d*d);
    if (l == 0) red2[w] = dv;
    __syncthreads();
    float rstd = rsqrtf((red2[0]+red2[1]+red2[2]+red2[3])*(1.f/256.f) + 1e-5f);
    float yv = d*rstd*g2[tid] + b2[tid];
    yy[tid] = yv;
    __syncthreads();
    float s2 = 0.f;
    for (int c = 0; c < 256; c++) s2 += yy[c]*wmlp[tid*256 + c];
    outf[tid] = s2 + bias[tid] + pv;
    return;
  }

  const int rbase = blockIdx.x*64 + w*16;
  const size_t ar = (size_t)(1 + rbase + lq);
  const float mean_a = mrA[ar*2+0];
  const float rstd_a = mrA[ar*2+1];
  const int fr = rbase + lq;

  // ---- GEMM#1 prologue: stage Bp1[0]->buf0, Bp1[1]->buf1 ----
#pragma unroll
  for (int i=0;i<4;i++)
    gload_lds16(Bp1 + (((i<<2)+w)<<9) + l*8, bsh + (((i<<2)+w)<<9));
#pragma unroll
  for (int i=0;i<4;i++)
    gload_lds16(Bp1 + 8192 + (((i<<2)+w)<<9) + l*8, bsh + 8192 + (((i<<2)+w)<<9));

  // ---- A-build #1: from p1b (bf16) + MR1 stats + ln_s + attn weights ----
  bf16x8 av[8];
#pragma unroll
  for (int kk=0;kk<8;kk++){
    const int co = kk*32 + q*8;
    bf16x8 u = *(const bf16x8*)(p1b + ar*256 + co);
    f32x4 ga0 = *(const f32x4*)(gA + co), ga1 = *(const f32x4*)(gA + co + 4);
    f32x4 ba0 = *(const f32x4*)(bA + co), ba1 = *(const f32x4*)(bA + co + 4);
    bf16x8 y0v = *(const bf16x8*)(y0bf_in + co);
    const float A  = awsv[kk*NFR + fr];
    const float A0 = aw0sv[(kk<<10) + (fr>>d1shift)];
#pragma unroll
    for (int j=0;j<4;j++){
      float yv = ((float)u[j]-mean_a)*rstd_a*ga0[j] + ba0[j];
      av[kk][j] = (__bf16)(A*yv + A0*(float)y0v[j]);
    }
#pragma unroll
    for (int j=0;j<4;j++){
      float yv = ((float)u[4+j]-mean_a)*rstd_a*ga1[j] + ba1[j];
      av[kk][4+j] = (__bf16)(A*yv + A0*(float)y0v[4+j]);
    }
  }

  __syncthreads();   // drain prologue: loop-entry outstanding VMEM = 0

  // ---- GEMM#1: hardened counted-vmcnt pipeline ----
  f32x4 acc[16];
  const f32x4 zero = {0.f,0.f,0.f,0.f};
#pragma unroll
  for (int ct=0;ct<16;ct++) acc[ct]=zero;
#pragma unroll
  for (int kk=0;kk<8;kk++){
    __builtin_amdgcn_sched_barrier(0);
    if (kk<7) asm volatile("s_waitcnt vmcnt(4)\n\ts_barrier" ::: "memory");
    else      asm volatile("s_waitcnt vmcnt(0)\n\ts_barrier" ::: "memory");
    __builtin_amdgcn_sched_barrier(0);
    if (kk<6){
#pragma unroll
      for (int i=0;i<4;i++)
        gload_lds16(Bp1 + (size_t)(kk+2)*8192 + (((i<<2)+w)<<9) + l*8,
                    bsh + ((kk+2)%3)*8192 + (((i<<2)+w)<<9));
    }
#pragma unroll
    for (int ct=0;ct<16;ct++){
      bf16x8 bfv = *(const bf16x8*)(bsh + (kk%3)*8192 + (((ct<<6)+l)<<3));
      acc[ct] = __builtin_amdgcn_mfma_f32_16x16x32_bf16(av[kk], bfv, acc[ct], 0,0,0);
    }
  }
  __builtin_amdgcn_sched_barrier(0);
  __syncthreads();   // B reads done; bufs become f32 scratch

  // ---- Epilogue #1: acc -> p2 (residual from p1b); bf16 p2 -> tileA; LN_m stats -> mrS ----
  char* myl = smem + w*8192;
#pragma unroll
  for (int h=0; h<2; h++){
    if (h) __syncthreads();
    if ((q>>1) == h){
      const int rl0 = (q&1)*4;
#pragma unroll
      for (int ct=0;ct<16;ct++){
#pragma unroll
        for (int rr=0;rr<4;rr++){
          int rl = rl0 + rr;
          unsigned byte = (unsigned)(rl*1024 + ct*64 + lq*4);
          *(float*)(myl + (byte ^ ((unsigned)(rl&7)<<4))) = acc[ct][rr];
        }
      }
    }
    __syncthreads();

#pragma unroll
    for (int i=0;i<8;i++){
      unsigned byte = (unsigned)(i*1024 + l*16);
      char* ap = myl + (byte ^ ((unsigned)(i&7)<<4));
      f32x4 cv = *(f32x4*)ap;
      const size_t grow = (size_t)(1 + rbase + h*8 + i);
      bf16x4 xr = *(const bf16x4*)(p1b + grow*256 + l*4);
      cv[0]+=(float)xr[0]; cv[1]+=(float)xr[1]; cv[2]+=(float)xr[2]; cv[3]+=(float)xr[3];
      *(f32x4*)ap = cv;
      bf16x4 ob; ob[0]=(__bf16)cv[0]; ob[1]=(__bf16)cv[1]; ob[2]=(__bf16)cv[2]; ob[3]=(__bf16)cv[3];
      unsigned tb = (unsigned)((h*8+i)*512 + l*8);
      *(bf16x4*)(tAw + (tb ^ ((unsigned)(i&7)<<4))) = ob;
    }

#pragma unroll
    for (int it=0; it<2; it++){
      int rl = it*4 + q;
      f32x4 v[4];
#pragma unroll
      for (int p=0;p<4;p++){
        unsigned byte = (unsigned)(rl*1024 + p*256 + lq*16);
        v[p] = *(f32x4*)(myl + (byte ^ ((unsigned)(rl&7)<<4)));
      }
      float s = 0.f;
#pragma unroll
      for (int p=0;p<4;p++) s += v[p][0]+v[p][1]+v[p][2]+v[p][3];
      s += __shfl_xor(s,1); s += __shfl_xor(s,2); s += __shfl_xor(s,4); s += __shfl_xor(s,8);
      float mean = s * (1.f/256.f);
      float ss = 0.f;
#pragma unroll
      for (int p=0;p<4;p++){
        float a0=v[p][0]-mean,a1=v[p][1]-mean,a2=v[p][2]-mean,a3=v[p][3]-mean;
        ss += a0*a0+a1*a1+a2*a2+a3*a3;
      }
      ss += __shfl_xor(ss,1); ss += __shfl_xor(ss,2); ss += __shfl_xor(ss,4); ss += __shfl_xor(ss,8);
      float rstd = rsqrtf(ss*(1.f/256.f) + 1e-5f);
      if (lq == 0){
        mrS[(w*16 + h*8 + rl)*2+0] = mean;
        mrS[(w*16 + h*8 + rl)*2+1] = rstd;
      }
    }
  }
  __syncthreads();   // scratch reads done before Bp2 staging overwrites [0,32KB)

  // ---- GEMM#2 prologue: stage Bp2[0]->buf0, Bp2[1]->buf1 ----
#pragma unroll
  for (int i=0;i<4;i++)
    gload_lds16(Bp2 + (((i<<2)+w)<<9) + l*8, bsh + (((i<<2)+w)<<9));
#pragma unroll
  for (int i=0;i<4;i++)
    gload_lds16(Bp2 + 8192 + (((i<<2)+w)<<9) + l*8, bsh + 8192 + (((i<<2)+w)<<9));

  // ---- A-build #2: LN_m(p2) from tileA + mrS (all wave-local LDS) ----
  const float mean2 = mrS[(w*16 + lq)*2+0];
  const float rstd2 = mrS[(w*16 + lq)*2+1];
  bf16x8 av2[8];
#pragma unroll
  for (int kk=0;kk<8;kk++){
    const int co = kk*32 + q*8;
    unsigned tb = (unsigned)(lq*512 + kk*64 + q*16);
    bf16x8 u = *(const bf16x8*)(tAw + (tb ^ ((unsigned)(lq&7)<<4)));
    f32x4 ga0 = *(const f32x4*)(g2 + co), ga1 = *(const f32x4*)(g2 + co + 4);
    f32x4 ba0 = *(const f32x4*)(b2 + co), ba1 = *(const f32x4*)(b2 + co + 4);
#pragma unroll
    for (int j=0;j<4;j++) av2[kk][j]   = (__bf16)(((float)u[j]  -mean2)*rstd2*ga0[j] + ba0[j]);
#pragma unroll
    for (int j=0;j<4;j++) av2[kk][4+j] = (__bf16)(((float)u[4+j]-mean2)*rstd2*ga1[j] + ba1[j]);
  }

  __syncthreads();   // drain GEMM#2 prologue

  // ---- GEMM#2: same hardened pipeline vs packed W_mlp ----
#pragma unroll
  for (int ct=0;ct<16;ct++) acc[ct]=zero;
#pragma unroll
  for (int kk=0;kk<8;kk++){
    __builtin_amdgcn_sched_barrier(0);
    if (kk<7) asm volatile("s_waitcnt vmcnt(4)\n\ts_barrier" ::: "memory");
    else      asm volatile("s_waitcnt vmcnt(0)\n\ts_barrier" ::: "memory");
    __builtin_amdgcn_sched_barrier(0);
    if (kk<6){
#pragma unroll
      for (int i=0;i<4;i++)
        gload_lds16(Bp2 + (size_t)(kk+2)*8192 + (((i<<2)+w)<<9) + l*8,
                    bsh + ((kk+2)%3)*8192 + (((i<<2)+w)<<9));
    }
#pragma unroll
    for (int ct=0;ct<16;ct++){
      bf16x8 bfv = *(const bf16x8*)(bsh + (kk%3)*8192 + (((ct<<6)+l)<<3));
      acc[ct] = __builtin_amdgcn_mfma_f32_16x16x32_bf16(av2[kk], bfv, acc[ct], 0,0,0);
    }
  }
  __builtin_amdgcn_sched_barrier(0);
  __syncthreads();   // B reads done; bufs -> f32 scratch again

  // ---- Epilogue #2 (gemmL-style): out = acc + p2(tileA) + bias, f32 coalesced ----
#pragma unroll
  for (int h2=0;h2<2;h2++){
    if (h2) __syncthreads();
#pragma unroll
    for (int ct=0;ct<8;ct++){
      int ctg = h2*8+ct;
#pragma unroll
      for (int rr=0;rr<4;rr++){
        int row = q*4+rr;
        unsigned byte = (unsigned)(row*512 + ct*64 + lq*4);
        *(float*)(myl + (byte ^ ((unsigned)(row&7)<<4))) = acc[ctg][rr];
      }
    }
    __syncthreads();
#pragma unroll
    for (int i=0;i<8;i++){
      int lin = i*64 + l;
      int row = lin>>5, c4 = lin&31;
      unsigned byte = (unsigned)(row*512 + c4*16);
      f32x4 cv = *(f32x4*)(myl + (byte ^ ((unsigned)(row&7)<<4)));
      const size_t grow = (size_t)(1 + rbase + row);
      int col = h2*128 + c4*4;
      unsigned tb = (unsigned)(row*512 + col*2);
      bf16x4 xr = *(const bf16x4*)(tAw + (tb ^ ((unsigned)(row&7)<<4)));
      const float4 bb = *(const float4*)(bias + col);
      *(float4*)(outf + grow*256 + col) =
          make_float4(cv[0]+(float)xr[0]+bb.x, cv[1]+(float)xr[1]+bb.y,
                      cv[2]+(float)xr[2]+bb.z, cv[3]+(float)xr[3]+bb.w);
    }
  }
}

extern "C" void kernel_launch(void* const* d_in, const int* in_sizes, int n_in,
                              void* d_out, int out_size, void* d_ws, size_t ws_size,
                              hipStream_t stream){
  const float* emb    = (const float*)d_in[0];
  const float* ln_t_g = (const float*)d_in[1];
  const float* ln_t_b = (const float*)d_in[2];
  const float* Wq_t   = (const float*)d_in[3];
  const float* Wk_t   = (const float*)d_in[4];
  const float* Wv_t   = (const float*)d_in[5];
  const float* Wt_t   = (const float*)d_in[6];
  const float* ln_s_g = (const float*)d_in[7];
  const float* ln_s_b = (const float*)d_in[8];
  const float* Wq_s   = (const float*)d_in[9];
  const float* Wk_s   = (const float*)d_in[10];
  const float* Wv_s   = (const float*)d_in[11];
  const float* Wt_s   = (const float*)d_in[12];
  const float* ln_m_g = (const float*)d_in[13];
  const float* ln_m_b = (const float*)d_in[14];
  const float* W_mlp  = (const float*)d_in[15];
  const float* b_mlp  = (const float*)d_in[16];
  float* outf = (float*)d_out;

  // ---- d_out overlay: MR0 only (dead before k_gemmFL writes all of d_out) ----
  float*  MR0 = outf + 8388736;              // 131074 f32

  // ---- workspace layout ----
  float* W      = (float*)d_ws;
  float* SUMS   = W;                         // 64
  float* THAT1  = W + 64;                    // 64 (raw, unscaled)
  float* THAT2  = W + 128;                   // 64
  float* Y0F1   = W + 192;                   // 256
  float* Y0F2   = W + 448;                   // 256
  float* TOKAC1 = W + 704;                   // 256
  float* TOKAC2 = W + 960;                   // 256 (dead; kept for gemmF1 signature)
  float* AW0    = W + 1216;                  // 8192
  float* SPL    = W + 9408;                  // 524288 (phase-2 splane only)
  float* AWSV   = W + 533696;                // 524288
  float* PGRP   = W + 1057984;               // 262144 (ph1 by k_score, ph2 by gemmF1)
  float* MR1    = W + 1320128;               // 131074 (reserve 131104)
  __bf16* BFB   = (__bf16*)(W + 1451232);
  __bf16* PT    = BFB;                       // packed Wt_t fragments (65536)
  __bf16* PS    = BFB + 65536;               // packed Wt_s fragments
  __bf16* PM    = BFB + 131072;              // packed W_mlp fragments
  __bf16* Y0BF1 = BFB + 196608;              // 256
  __bf16* Y0BF2 = BFB + 196864;              // 256
  __bf16* P1B   = BFB + 197120;              // 65537*256 bf16

  k_prep<<<103,256,0,stream>>>(Wq_t,Wk_t,Wv_t,Wq_s,Wk_s,Wv_s,Wt_t,Wt_s,W_mlp,
                               emb, ln_t_g, ln_t_b,
                               SUMS, THAT1, Y0F1, Y0BF1, TOKAC1, PT,PS,PM);

  // ---- phase 1: LN/scores + in-block softmax (k_softmax<1> fused in); pgrp partials out ----
  k_score<<<1024,256,0,stream>>>(emb, ln_t_g, ln_t_b, SUMS, 0, THAT1, AWSV, AW0, PGRP, MR0);
  k_tok1<<<32,256,0,stream>>>(PGRP, AW0, TOKAC1, 0);

  // ---- phase-1 GEMM (p1b bf16 -> WS) + fused phase-2 LN/score epilogue ----
  k_gemmF<1><<<1025,256,0,stream>>>(emb, nullptr, P1B, PT, MR0, ln_t_g, ln_t_b,
                                    Y0BF1, AWSV, AW0, 6, SUMS, 0, Wt_t, Y0F1, TOKAC1,
                                    ln_s_g, ln_s_b, MR1,
                                    THAT2, Y0F2, Y0BF2, TOKAC2, SPL, PGRP);
  k_softmax<16><<<128,256,0,stream>>>(SPL, THAT2, SUMS, 1, AWSV, AW0, 512);

  // ---- fused phase-2 GEMM + final GEMM (k_tok1 ph2 folded into token block) ----
  k_gemmFL<<<1025,256,0,stream>>>(P1B, outf, PS, PM, MR1, ln_s_g, ln_s_b,
                                  Y0BF2, AWSV, AW0, 10, SUMS, 1, Wt_s, Y0F2, PGRP,
                                  ln_m_g, ln_m_b, W_mlp, b_mlp);
}

// Round 15
// 139.212 us; speedup vs baseline: 1.4841x; 1.4841x over previous
//
#include <hip/hip_runtime.h>
#include <hip/hip_bf16.h>

#define NROWS 65537
#define NFR   65536
#define EDIM  256

typedef __bf16 bf16x8 __attribute__((ext_vector_type(8)));
typedef __bf16 bf16x4 __attribute__((ext_vector_type(4)));
typedef float  f32x4  __attribute__((ext_vector_type(4)));

#define INV_SQRT_HD 0.17677669529663687f  // 1/sqrt(32)

__device__ __forceinline__ float wsum64(float v){
#pragma unroll
  for (int m = 1; m < 64; m <<= 1) v += __shfl_xor(v, m);
  return v;
}
__device__ __forceinline__ float wmax64(float v){
#pragma unroll
  for (int m = 1; m < 64; m <<= 1) v = fmaxf(v, __shfl_xor(v, m));
  return v;
}

// async global->LDS, 16B per lane; LDS dest is wave-uniform base + lane*16 (HW-added)
__device__ __forceinline__ void gload_lds16(const void* g, void* l){
  __builtin_amdgcn_global_load_lds(
      (const __attribute__((address_space(1))) void*)g,
      (__attribute__((address_space(3))) void*)l, 16, 0, 0);
}

// ---------- fused prep: weight sums + MFMA-fragment packing + phase-1 token LN ----------
__global__ __launch_bounds__(256) void k_prep(
    const float* __restrict__ wqt, const float* __restrict__ wkt, const float* __restrict__ wvt,
    const float* __restrict__ wqs, const float* __restrict__ wks, const float* __restrict__ wvs,
    const float* __restrict__ wt_t, const float* __restrict__ wt_s, const float* __restrict__ wmlp_f,
    const float* __restrict__ emb, const float* __restrict__ ltg, const float* __restrict__ ltb,
    float* __restrict__ sums, float* __restrict__ that1raw,
    float* __restrict__ y0f, __bf16* __restrict__ y0bf, float* __restrict__ tokacc,
    __bf16* __restrict__ pT, __bf16* __restrict__ pS, __bf16* __restrict__ pM){
  const int tid = threadIdx.x;
  if (blockIdx.x == 102){               // token row LN_t (one wave; no SUMS dependency)
    if (tid >= 64) return;
    const int l = tid;
    int c0 = l*4;
    const float4 xv = *(const float4*)(emb + c0);
    float mean = wsum64(xv.x+xv.y+xv.z+xv.w) * (1.f/256.f);
    float d0=xv.x-mean, d1=xv.y-mean, d2=xv.z-mean, d3=xv.w-mean;
    float rstd = rsqrtf(wsum64(d0*d0+d1*d1+d2*d2+d3*d3)*(1.f/256.f) + 1e-5f);
    const float4 gv = *(const float4*)(ltg + c0);
    const float4 bv = *(const float4*)(ltb + c0);
    float y0 = d0*rstd*gv.x+bv.x, y1 = d1*rstd*gv.y+bv.y;
    float y2 = d2*rstd*gv.z+bv.z, y3 = d3*rstd*gv.w+bv.w;
    float hs = y0*y0+y1*y1+y2*y2+y3*y3;
    hs += __shfl_xor(hs,1); hs += __shfl_xor(hs,2); hs += __shfl_xor(hs,4);
    if ((l & 7) == 0) that1raw[l>>3] = hs;          // RAW (c1 applied in k_score)
    y0f[c0+0]=y0; y0f[c0+1]=y1; y0f[c0+2]=y2; y0f[c0+3]=y3;
    y0bf[c0+0]=(__bf16)y0; y0bf[c0+1]=(__bf16)y1; y0bf[c0+2]=(__bf16)y2; y0bf[c0+3]=(__bf16)y3;
    tokacc[c0+0]=0.f; tokacc[c0+1]=0.f; tokacc[c0+2]=0.f; tokacc[c0+3]=0.f;
    return;
  }
  if (blockIdx.x < 6){
    const float* arr[6] = {wqt,wkt,wvt,wqs,wks,wvs};
    const float* p = arr[blockIdx.x];
    float s = 0.f;
#pragma unroll
    for (int k = 0; k < 8; k++){
      float4 v = *(const float4*)(p + (tid + k*256)*4);
      s += v.x+v.y+v.z+v.w;
    }
    s = wsum64(s);
    __shared__ float red[4];
    if ((tid & 63) == 0) red[tid>>6] = s;
    __syncthreads();
    if (tid == 0) sums[blockIdx.x] = red[0]+red[1]+red[2]+red[3];
    return;
  }
  int t = (blockIdx.x-6)*256 + tid;   // 96*256 = 3*8192 fragments
  int m = t >> 13, fi = t & 8191;
  int l = fi & 63, ct = (fi>>6)&15, kk = fi>>10;
  int n  = ct*16 + (l&15);
  int kb = kk*32 + ((l>>4)<<3);
  if (m == 0){
#pragma unroll
    for (int j=0;j<8;j++) pT[(size_t)fi*8+j] = (__bf16)wt_t[(kb+j)*256 + n];
  } else if (m == 1){
#pragma unroll
    for (int j=0;j<8;j++) pS[(size_t)fi*8+j] = (__bf16)wt_s[(kb+j)*256 + n];
  } else {
#pragma unroll
    for (int j=0;j<8;j++) pM[(size_t)fi*8+j] = (__bf16)wmlp_f[n*256 + kb + j];
  }
}

// ---------- phase-1 frames: LN -> mr0 + IN-BLOCK group softmax -> awsv/aw0 + pgrp partials ----------
__global__ __launch_bounds__(256) void k_score(
    const float* __restrict__ x, const float* __restrict__ g, const float* __restrict__ b,
    const float* __restrict__ S, int si,
    const float* __restrict__ that1raw,
    float* __restrict__ awsv, float* __restrict__ aw0sv,
    float* __restrict__ pgrp, float* __restrict__ mr0){
  const float c1 = S[3*si]*S[3*si+1]*INV_SQRT_HD;
  const int tid = threadIdx.x, w = tid>>6, l = tid&63;
  const int lq = l&15, q = l>>4;

  __shared__ float sLds[8][64];
  __shared__ float gsLds[4][256];
  const int chunk = blockIdx.x;          // 1024 blocks x 64 frames == softmax groups
  float4 gvv[4], bvv[4];
#pragma unroll
  for (int p=0;p<4;p++){
    gvv[p] = *(const float4*)(g + p*64 + lq*4);
    bvv[p] = *(const float4*)(b + p*64 + lq*4);
  }
  float gs[4][4];
#pragma unroll
  for (int p=0;p<4;p++){ gs[p][0]=0.f; gs[p][1]=0.f; gs[p][2]=0.f; gs[p][3]=0.f; }

#pragma unroll
  for (int it=0; it<4; it++){
    const int fo = w*16 + it*4 + q;     // frame within chunk
    const size_t grow = (size_t)(1 + chunk*64 + fo);
    float4 v[4];
#pragma unroll
    for (int p=0;p<4;p++) v[p] = *(const float4*)(x + grow*256 + p*64 + lq*4);
    float s = 0.f;
#pragma unroll
    for (int p=0;p<4;p++) s += v[p].x+v[p].y+v[p].z+v[p].w;
    s += __shfl_xor(s,1); s += __shfl_xor(s,2); s += __shfl_xor(s,4); s += __shfl_xor(s,8);
    const float mean = s * (1.f/256.f);
    float ss = 0.f;
#pragma unroll
    for (int p=0;p<4;p++){
      float a0=v[p].x-mean,a1=v[p].y-mean,a2=v[p].z-mean,a3=v[p].w-mean;
      ss += a0*a0+a1*a1+a2*a2+a3*a3;
    }
    ss += __shfl_xor(ss,1); ss += __shfl_xor(ss,2); ss += __shfl_xor(ss,4); ss += __shfl_xor(ss,8);
    const float rstd = rsqrtf(ss*(1.f/256.f) + 1e-5f);
    if (lq == 0){ mr0[grow*2+0] = mean; mr0[grow*2+1] = rstd; }
    float hs[4];
#pragma unroll
    for (int p=0;p<4;p++){
      float y0=(v[p].x-mean)*rstd*gvv[p].x+bvv[p].x;
      float y1=(v[p].y-mean)*rstd*gvv[p].y+bvv[p].y;
      float y2=(v[p].z-mean)*rstd*gvv[p].z+bvv[p].z;
      float y3=(v[p].w-mean)*rstd*gvv[p].w+bvv[p].w;
      gs[p][0]+=y0; gs[p][1]+=y1; gs[p][2]+=y2; gs[p][3]+=y3;
      hs[p] = y0*y0+y1*y1+y2*y2+y3*y3;
    }
#pragma unroll
    for (int p=0;p<4;p++){
      hs[p] += __shfl_xor(hs[p],1); hs[p] += __shfl_xor(hs[p],2); hs[p] += __shfl_xor(hs[p],4);
    }
    if ((lq & 7) == 0){
#pragma unroll
      for (int p=0;p<4;p++) sLds[2*p + (lq>>3)][fo] = c1*hs[p];
    }
  }
#pragma unroll
  for (int p=0;p<4;p++)
#pragma unroll
    for (int j=0;j<4;j++){
      gs[p][j] += __shfl_xor(gs[p][j], 16);
      gs[p][j] += __shfl_xor(gs[p][j], 32);
    }
  if (q == 0){
#pragma unroll
    for (int p=0;p<4;p++)
#pragma unroll
      for (int j=0;j<4;j++) gsLds[w][p*64 + lq*4 + j] = gs[p][j];
  }
  __syncthreads();

  // ---- in-block group softmax: wave w handles heads 2w, 2w+1 ----
#pragma unroll
  for (int hh=0; hh<2; hh++){
    const int h = w*2 + hh;
    float v = sLds[h][l];
    float tv = c1 * that1raw[h];
    float m = fmaxf(wmax64(v), tv);
    float e = __expf(v - m);
    float se = wsum64(e);
    float te = __expf(tv - m);
    float inv = S[3*si+2] / (se + te);
    awsv[h*NFR + chunk*64 + l] = e*inv;
    if (l == 0) aw0sv[(h<<10) + chunk] = te*inv;
  }

  // ---- per-chunk column-sum partials (reduced by k_tok1; no atomic storm) ----
  pgrp[chunk*256 + tid] = gsLds[0][tid]+gsLds[1][tid]+gsLds[2][tid]+gsLds[3][tid];
}

// ---------- group softmax (phase-2 only) -> per-row aw*sv planes + per-group aw0*sv ----------
template<int REPS>
__global__ __launch_bounds__(256) void k_softmax(
    const float* __restrict__ splane, const float* __restrict__ that,
    const float* __restrict__ S, int si,
    float* __restrict__ awsv, float* __restrict__ aw0sv, int nwaves){
  const int w = threadIdx.x>>6, l = threadIdx.x&63;
  const int gw = blockIdx.x*4 + w;
  if (gw >= nwaves) return;
  const int h = gw & 7, a = gw >> 3;
  const int base = a*(REPS*64);
  const float tv = that[h];
  float vals[REPS];
  float m = tv;
#pragma unroll
  for (int j = 0; j < REPS; j++){ vals[j] = splane[h*NFR + base + j*64 + l]; m = fmaxf(m, vals[j]); }
  m = wmax64(m);
  float se = 0.f;
#pragma unroll
  for (int j = 0; j < REPS; j++){ vals[j] = __expf(vals[j]-m); se += vals[j]; }
  se = wsum64(se);
  const float te = __expf(tv - m);
  const float inv = S[3*si+2] / (se + te);
#pragma unroll
  for (int j = 0; j < REPS; j++) awsv[h*NFR + base + j*64 + l] = vals[j]*inv;
  if (l == 0) aw0sv[(h<<10) + a] = te*inv;
}

// ---------- weighted reduce of partial group sums into the tok accumulator ----------
__global__ void k_tok1(const float* __restrict__ pgrp, const float* __restrict__ aw0sv,
                       float* __restrict__ tokacc, int cshift){
  const int c = threadIdx.x, h = c>>5;
  float acc = 0.f;
  const int cbase = blockIdx.x*32;      // 32 blocks x 32 chunks
  for (int k = 0; k < 32; k++){
    int chunk = cbase + k;
    acc += aw0sv[(h<<10) + (chunk>>cshift)] * pgrp[chunk*256 + c];
  }
  atomicAdd(&tokacc[c], acc);
}

// ---------- fused attn GEMM with LN-epilogue (phase 1 only; round-9 proven) ----------
template<int PH>
__global__ __launch_bounds__(256,3) void k_gemmF(
    const float* __restrict__ xf, const __bf16* __restrict__ xb,
    __bf16* __restrict__ outb,
    const __bf16* __restrict__ Bp, const float* __restrict__ mrA,
    const float* __restrict__ gA, const float* __restrict__ bA,
    const __bf16* __restrict__ y0bf_in,
    const float* __restrict__ awsv, const float* __restrict__ aw0sv, int d1shift,
    const float* __restrict__ S, int si,
    const float* __restrict__ Wt_f32, const float* __restrict__ y0f_in,
    const float* __restrict__ tokacc_in,
    const float* __restrict__ g2, const float* __restrict__ b2,
    float* __restrict__ mrOut,
    float* __restrict__ that_out, float* __restrict__ y0f_out,
    __bf16* __restrict__ y0bf_out, float* __restrict__ tokacc_out,
    float* __restrict__ splane, float* __restrict__ pgrp)
{
  const int tid = threadIdx.x, w = tid>>6, l = tid&63;
  const int lq = l&15, q = l>>4;

  __shared__ char smem[49152];                 // 3x16KB B bufs during MFMA; tile+sH+gsL after
  __shared__ float mr[4][8][2];
  __bf16* bsh = (__bf16*)smem;
  float* sH  = (float*)(smem + 32768);         // [8][64], PH1 only (3rd buf, dead post-loop)
  float* gsL = (float*)(smem + 32768 + 2048);  // [4][256], PH1 only

  if (blockIdx.x == 1024){   // token row (aliases onto smem/mr)
    float* tok  = (float*)smem;                  // 256 f32
    float* yy   = (float*)(smem + 1024);         // 256 f32
    float* red  = &mr[0][0][0];                  // 4 f32
    float* red2 = &mr[1][0][0];                  // 4 f32
    tok[tid] = S[3*si+2]*y0f_in[tid] + tokacc_in[tid];
    __syncthreads();
    float s = 0.f;
    for (int c = 0; c < 256; c++) s += tok[c]*Wt_f32[c*256 + tid];
    float pv = s + ((PH==1) ? xf[tid] : (float)xb[tid]);   // new row-0 value
    outb[tid] = (__bf16)pv;
    float sw = wsum64(pv);
    if (l == 0) red[w] = sw;
    __syncthreads();
    float mean = (red[0]+red[1]+red[2]+red[3]) * (1.f/256.f);
    float d = pv - mean;
    float dv = wsum64(d*d);
    if (l == 0) red2[w] = dv;
    __syncthreads();
    float rstd = rsqrtf((red2[0]+red2[1]+red2[2]+red2[3])*(1.f/256.f) + 1e-5f);
    if (PH == 1){
      float yv = d*rstd*g2[tid] + b2[tid];
      yy[tid] = yv*yv;
      y0f_out[tid] = yv;
      y0bf_out[tid] = (__bf16)yv;
      tokacc_out[tid] = 0.f;
      __syncthreads();
      if (tid < 8){
        float hsum = 0.f;
        for (int c = 0; c < 32; c++) hsum += yy[tid*32 + c];
        const float c1n = S[3*(si+1)]*S[3*(si+1)+1]*INV_SQRT_HD;
        that_out[tid] = c1n*hsum;
      }
    } else {
      if (tid == 0){ mrOut[0] = mean; mrOut[1] = rstd; }
    }
    return;
  }

  const int rbase = blockIdx.x*64 + w*16;        // frame base of this wave
  const size_t ar = (size_t)(1 + rbase + lq);
  const float mean_a = mrA[ar*2+0];
  const float rstd_a = mrA[ar*2+1];
  const int fr = rbase + lq;

  // ---- prologue: stage B[0]->buf0 and B[1]->buf1; wave w covers 4 x 1KB slices each ----
#pragma unroll
  for (int i=0;i<4;i++)
    gload_lds16(Bp + (((i<<2)+w)<<9) + l*8, bsh + (((i<<2)+w)<<9));
#pragma unroll
  for (int i=0;i<4;i++)
    gload_lds16(Bp + 8192 + (((i<<2)+w)<<9) + l*8, bsh + 8192 + (((i<<2)+w)<<9));

  // ---- hoisted A-side: build all 8 av fragments before the kk loop ----
  bf16x8 av[8];
#pragma unroll
  for (int kk=0;kk<8;kk++){
    const int co = kk*32 + q*8;
    float va[8];
    if (PH==1){
      f32x4 u0 = *(const f32x4*)(xf + ar*256 + co);
      f32x4 u1 = *(const f32x4*)(xf + ar*256 + co + 4);
#pragma unroll
      for (int j=0;j<4;j++){ va[j]=u0[j]; va[4+j]=u1[j]; }
    } else {
      bf16x8 u = *(const bf16x8*)(xb + ar*256 + co);
#pragma unroll
      for (int j=0;j<8;j++) va[j]=(float)u[j];
    }
    f32x4 ga0 = *(const f32x4*)(gA + co), ga1 = *(const f32x4*)(gA + co + 4);
    f32x4 ba0 = *(const f32x4*)(bA + co), ba1 = *(const f32x4*)(bA + co + 4);
    bf16x8 y0v = *(const bf16x8*)(y0bf_in + co);
    const float A  = awsv[kk*NFR + fr];
    const float A0 = aw0sv[(kk<<10) + (fr>>d1shift)];
#pragma unroll
    for (int j=0;j<4;j++){
      float yv = (va[j]-mean_a)*rstd_a*ga0[j] + ba0[j];
      av[kk][j] = (__bf16)(A*yv + A0*(float)y0v[j]);
    }
#pragma unroll
    for (int j=0;j<4;j++){
      float yv = (va[4+j]-mean_a)*rstd_a*ga1[j] + ba1[j];
      av[kk][4+j] = (__bf16)(A*yv + A0*(float)y0v[4+j]);
    }
  }

  // ---- drain prologue completely: loop-entry outstanding VMEM = 0 for every wave ----
  __syncthreads();

  // ---- MFMA loop: counted vmcnt, fused wait+barrier asm, sched fences both sides ----
  f32x4 acc[16];
  const f32x4 zero = {0.f,0.f,0.f,0.f};
#pragma unroll
  for (int ct=0;ct<16;ct++) acc[ct]=zero;
#pragma unroll
  for (int kk=0;kk<8;kk++){
    __builtin_amdgcn_sched_barrier(0);
    if (kk<7) asm volatile("s_waitcnt vmcnt(4)\n\ts_barrier" ::: "memory");
    else      asm volatile("s_waitcnt vmcnt(0)\n\ts_barrier" ::: "memory");
    __builtin_amdgcn_sched_barrier(0);
    if (kk<6){
#pragma unroll
      for (int i=0;i<4;i++)
        gload_lds16(Bp + (size_t)(kk+2)*8192 + (((i<<2)+w)<<9) + l*8,
                    bsh + ((kk+2)%3)*8192 + (((i<<2)+w)<<9));
    }
#pragma unroll
    for (int ct=0;ct<16;ct++){
      bf16x8 bfv = *(const bf16x8*)(bsh + (kk%3)*8192 + (((ct<<6)+l)<<3));
      acc[ct] = __builtin_amdgcn_mfma_f32_16x16x32_bf16(av[kk], bfv, acc[ct], 0,0,0);
    }
  }
  __builtin_amdgcn_sched_barrier(0);
  __syncthreads();                  // all B reads done before smem is reused as the tile

  char* myl = smem + w*8192;
  const float4 gvc = *(const float4*)(g2 + l*4);
  const float4 bvc = *(const float4*)(b2 + l*4);
  float gs0=0.f, gs1=0.f, gs2=0.f, gs3=0.f;
  const float c1n = (PH==1) ? S[3*(si+1)]*S[3*(si+1)+1]*INV_SQRT_HD : 0.f;

#pragma unroll
  for (int h=0; h<2; h++){
    if (h) __syncthreads();
    if ((q>>1) == h){
      const int rl0 = (q&1)*4;
#pragma unroll
      for (int ct=0;ct<16;ct++){
#pragma unroll
        for (int rr=0;rr<4;rr++){
          int rl = rl0 + rr;
          unsigned byte = (unsigned)(rl*1024 + ct*64 + lq*4);
          *(float*)(myl + (byte ^ ((unsigned)(rl&7)<<4))) = acc[ct][rr];
        }
      }
    }
    __syncthreads();

#pragma unroll
    for (int i=0;i<8;i++){
      unsigned byte = (unsigned)(i*1024 + l*16);
      char* ap = myl + (byte ^ ((unsigned)(i&7)<<4));
      f32x4 cv = *(f32x4*)ap;
      const size_t grow = (size_t)(1 + rbase + h*8 + i);
      if (PH==1){
        const float4 xr = *(const float4*)(xf + grow*256 + l*4);
        cv[0]+=xr.x; cv[1]+=xr.y; cv[2]+=xr.z; cv[3]+=xr.w;
      } else {
        bf16x4 xr = *(const bf16x4*)(xb + grow*256 + l*4);
        cv[0]+=(float)xr[0]; cv[1]+=(float)xr[1]; cv[2]+=(float)xr[2]; cv[3]+=(float)xr[3];
      }
      *(f32x4*)ap = cv;
      bf16x4 ob; ob[0]=(__bf16)cv[0]; ob[1]=(__bf16)cv[1]; ob[2]=(__bf16)cv[2]; ob[3]=(__bf16)cv[3];
      *(bf16x4*)(outb + grow*256 + l*4) = ob;
    }

#pragma unroll
    for (int it=0; it<2; it++){
      int rl = it*4 + q;
      f32x4 v[4];
#pragma unroll
      for (int p=0;p<4;p++){
        unsigned byte = (unsigned)(rl*1024 + p*256 + lq*16);
        v[p] = *(f32x4*)(myl + (byte ^ ((unsigned)(rl&7)<<4)));
      }
      float s = 0.f;
#pragma unroll
      for (int p=0;p<4;p++) s += v[p][0]+v[p][1]+v[p][2]+v[p][3];
      s += __shfl_xor(s,1); s += __shfl_xor(s,2); s += __shfl_xor(s,4); s += __shfl_xor(s,8);
      float mean = s * (1.f/256.f);
      float ss = 0.f;
#pragma unroll
      for (int p=0;p<4;p++){
        float a0=v[p][0]-mean,a1=v[p][1]-mean,a2=v[p][2]-mean,a3=v[p][3]-mean;
        ss += a0*a0+a1*a1+a2*a2+a3*a3;
      }
      ss += __shfl_xor(ss,1); ss += __shfl_xor(ss,2); ss += __shfl_xor(ss,4); ss += __shfl_xor(ss,8);
      float rstd = rsqrtf(ss*(1.f/256.f) + 1e-5f);
      if (lq == 0){
        if (PH==1){ mr[w][rl][0] = mean; mr[w][rl][1] = rstd; }
        const size_t gr = (size_t)(1 + rbase + h*8 + rl);
        mrOut[gr*2+0] = mean; mrOut[gr*2+1] = rstd;
      }
    }

    if (PH==1){
#pragma unroll
      for (int i=0;i<8;i++){
        float mean = mr[w][i][0], rstd = mr[w][i][1];
        unsigned byte = (unsigned)(i*1024 + l*16);
        f32x4 cv = *(f32x4*)(myl + (byte ^ ((unsigned)(i&7)<<4)));
        float y0=(cv[0]-mean)*rstd*gvc.x+bvc.x;
        float y1=(cv[1]-mean)*rstd*gvc.y+bvc.y;
        float y2=(cv[2]-mean)*rstd*gvc.z+bvc.z;
        float y3=(cv[3]-mean)*rstd*gvc.w+bvc.w;
        gs0+=y0; gs1+=y1; gs2+=y2; gs3+=y3;
        float hp = y0*y0+y1*y1+y2*y2+y3*y3;
        hp += __shfl_xor(hp,1); hp += __shfl_xor(hp,2); hp += __shfl_xor(hp,4);
        if ((l & 7) == 0) sH[(l>>3)*64 + w*16 + h*8 + i] = c1n*hp;
      }
    }
  }

  if (PH==1){
    gsL[w*256 + l*4+0]=gs0; gsL[w*256 + l*4+1]=gs1; gsL[w*256 + l*4+2]=gs2; gsL[w*256 + l*4+3]=gs3;
    __syncthreads();
    pgrp[blockIdx.x*256 + tid] = gsL[0*256+tid]+gsL[1*256+tid]+gsL[2*256+tid]+gsL[3*256+tid];
#pragma unroll
    for (int rep = 0; rep < 2; rep++){
      int j = rep*256 + tid; int h = j>>6, fo = j&63;
      splane[h*NFR + blockIdx.x*64 + fo] = sH[h*64 + fo];
    }
  }
}

// ---------- fused phase-2 GEMM + final GEMM (round-11 proven) ----------
__global__ __launch_bounds__(256,2) void k_gemmFL(
    const __bf16* __restrict__ p1b,
    float* __restrict__ outf,
    const __bf16* __restrict__ Bp1,        // packed Wt_s
    const __bf16* __restrict__ Bp2,        // packed W_mlp
    const float* __restrict__ mrA,         // MR1
    const float* __restrict__ gA, const float* __restrict__ bA,   // ln_s
    const __bf16* __restrict__ y0bf_in,
    const float* __restrict__ awsv, const float* __restrict__ aw0sv, int d1shift,
    const float* __restrict__ S, int si,
    const float* __restrict__ Wt_f32,      // Wt_s (token)
    const float* __restrict__ y0f_in, const float* __restrict__ tokacc_in,
    const float* __restrict__ g2, const float* __restrict__ b2,   // ln_m
    const float* __restrict__ wmlp, const float* __restrict__ bias)
{
  const int tid = threadIdx.x, w = tid>>6, l = tid&63;
  const int lq = l&15, q = l>>4;

  __shared__ char smem[81920];
  __bf16* bsh  = (__bf16*)smem;
  float*  mrS  = (float*)(smem + 32768);
  char*   tAw  = smem + 49152 + w*8192;    // this wave's bf16 p2 tile

  if (blockIdx.x == 1024){   // token row: p2[0] + LN_m + final GEMM row 0, all scalar
    float* tok  = (float*)smem;            // 256
    float* yy   = (float*)(smem + 1024);   // 256
    float* red  = (float*)(smem + 2048);   // 4
    float* red2 = (float*)(smem + 2064);   // 4
    tok[tid] = S[3*si+2]*y0f_in[tid] + tokacc_in[tid];
    __syncthreads();
    float s = 0.f;
    for (int c = 0; c < 256; c++) s += tok[c]*Wt_f32[c*256 + tid];
    float pv = s + (float)p1b[tid];        // p2 row 0
    float sw = wsum64(pv);
    if (l == 0) red[w] = sw;
    __syncthreads();
    float mean = (red[0]+red[1]+red[2]+red[3]) * (1.f/256.f);
    float d = pv - mean;
    float dv = wsum64(d*d);
    if (l == 0) red2[w] = dv;
    __syncthreads();
    float rstd = rsqrtf((red2[0]+red2[1]+red2[2]+red2[3])*(1.f/256.f) + 1e-5f);
    float yv = d*rstd*g2[tid] + b2[tid];
    yy[tid] = yv;
    __syncthreads();
    float s2 = 0.f;
    for (int c = 0; c < 256; c++) s2 += yy[c]*wmlp[tid*256 + c];
    outf[tid] = s2 + bias[tid] + pv;
    return;
  }

  const int rbase = blockIdx.x*64 + w*16;
  const size_t ar = (size_t)(1 + rbase + lq);
  const float mean_a = mrA[ar*2+0];
  const float rstd_a = mrA[ar*2+1];
  const int fr = rbase + lq;

  // ---- GEMM#1 prologue: stage Bp1[0]->buf0, Bp1[1]->buf1 ----
#pragma unroll
  for (int i=0;i<4;i++)
    gload_lds16(Bp1 + (((i<<2)+w)<<9) + l*8, bsh + (((i<<2)+w)<<9));
#pragma unroll
  for (int i=0;i<4;i++)
    gload_lds16(Bp1 + 8192 + (((i<<2)+w)<<9) + l*8, bsh + 8192 + (((i<<2)+w)<<9));

  // ---- A-build #1: from p1b (bf16) + MR1 stats + ln_s + attn weights ----
  bf16x8 av[8];
#pragma unroll
  for (int kk=0;kk<8;kk++){
    const int co = kk*32 + q*8;
    bf16x8 u = *(const bf16x8*)(p1b + ar*256 + co);
    f32x4 ga0 = *(const f32x4*)(gA + co), ga1 = *(const f32x4*)(gA + co + 4);
    f32x4 ba0 = *(const f32x4*)(bA + co), ba1 = *(const f32x4*)(bA + co + 4);
    bf16x8 y0v = *(const bf16x8*)(y0bf_in + co);
    const float A  = awsv[kk*NFR + fr];
    const float A0 = aw0sv[(kk<<10) + (fr>>d1shift)];
#pragma unroll
    for (int j=0;j<4;j++){
      float yv = ((float)u[j]-mean_a)*rstd_a*ga0[j] + ba0[j];
      av[kk][j] = (__bf16)(A*yv + A0*(float)y0v[j]);
    }
#pragma unroll
    for (int j=0;j<4;j++){
      float yv = ((float)u[4+j]-mean_a)*rstd_a*ga1[j] + ba1[j];
      av[kk][4+j] = (__bf16)(A*yv + A0*(float)y0v[4+j]);
    }
  }

  __syncthreads();   // drain prologue: loop-entry outstanding VMEM = 0

  // ---- GEMM#1: hardened counted-vmcnt pipeline ----
  f32x4 acc[16];
  const f32x4 zero = {0.f,0.f,0.f,0.f};
#pragma unroll
  for (int ct=0;ct<16;ct++) acc[ct]=zero;
#pragma unroll
  for (int kk=0;kk<8;kk++){
    __builtin_amdgcn_sched_barrier(0);
    if (kk<7) asm volatile("s_waitcnt vmcnt(4)\n\ts_barrier" ::: "memory");
    else      asm volatile("s_waitcnt vmcnt(0)\n\ts_barrier" ::: "memory");
    __builtin_amdgcn_sched_barrier(0);
    if (kk<6){
#pragma unroll
      for (int i=0;i<4;i++)
        gload_lds16(Bp1 + (size_t)(kk+2)*8192 + (((i<<2)+w)<<9) + l*8,
                    bsh + ((kk+2)%3)*8192 + (((i<<2)+w)<<9));
    }
#pragma unroll
    for (int ct=0;ct<16;ct++){
      bf16x8 bfv = *(const bf16x8*)(bsh + (kk%3)*8192 + (((ct<<6)+l)<<3));
      acc[ct] = __builtin_amdgcn_mfma_f32_16x16x32_bf16(av[kk], bfv, acc[ct], 0,0,0);
    }
  }
  __builtin_amdgcn_sched_barrier(0);
  __syncthreads();   // B reads done; bufs become f32 scratch

  // ---- Epilogue #1: acc -> p2 (residual from p1b); bf16 p2 -> tileA; LN_m stats -> mrS ----
  char* myl = smem + w*8192;
#pragma unroll
  for (int h=0; h<2; h++){
    if (h) __syncthreads();
    if ((q>>1) == h){
      const int rl0 = (q&1)*4;
#pragma unroll
      for (int ct=0;ct<16;ct++){
#pragma unroll
        for (int rr=0;rr<4;rr++){
          int rl = rl0 + rr;
          unsigned byte = (unsigned)(rl*1024 + ct*64 + lq*4);
          *(float*)(myl + (byte ^ ((unsigned)(rl&7)<<4))) = acc[ct][rr];
        }
      }
    }
    __syncthreads();

#pragma unroll
    for (int i=0;i<8;i++){
      unsigned byte = (unsigned)(i*1024 + l*16);
      char* ap = myl + (byte ^ ((unsigned)(i&7)<<4));
      f32x4 cv = *(f32x4*)ap;
      const size_t grow = (size_t)(1 + rbase + h*8 + i);
      bf16x4 xr = *(const bf16x4*)(p1b + grow*256 + l*4);
      cv[0]+=(float)xr[0]; cv[1]+=(float)xr[1]; cv[2]+=(float)xr[2]; cv[3]+=(float)xr[3];
      *(f32x4*)ap = cv;
      bf16x4 ob; ob[0]=(__bf16)cv[0]; ob[1]=(__bf16)cv[1]; ob[2]=(__bf16)cv[2]; ob[3]=(__bf16)cv[3];
      unsigned tb = (unsigned)((h*8+i)*512 + l*8);
      *(bf16x4*)(tAw + (tb ^ ((unsigned)(i&7)<<4))) = ob;
    }

#pragma unroll
    for (int it=0; it<2; it++){
      int rl = it*4 + q;
      f32x4 v[4];
#pragma unroll
      for (int p=0;p<4;p++){
        unsigned byte = (unsigned)(rl*1024 + p*256 + lq*16);
        v[p] = *(f32x4*)(myl + (byte ^ ((unsigned)(rl&7)<<4)));
      }
      float s = 0.f;
#pragma unroll
      for (int p=0;p<4;p++) s += v[p][0]+v[p][1]+v[p][2]+v[p][3];
      s += __shfl_xor(s,1); s += __shfl_xor(s,2); s += __shfl_xor(s,4); s += __shfl_xor(s,8);
      float mean = s * (1.f/256.f);
      float ss = 0.f;
#pragma unroll
      for (int p=0;p<4;p++){
        float a0=v[p][0]-mean,a1=v[p][1]-mean,a2=v[p][2]-mean,a3=v[p][3]-mean;
        ss += a0*a0+a1*a1+a2*a2+a3*a3;
      }
      ss += __shfl_xor(ss,1); ss += __shfl_xor(ss,2); ss += __shfl_xor(ss,4); ss += __shfl_xor(ss,8);
      float rstd = rsqrtf(ss*(1.f/256.f) + 1e-5f);
      if (lq == 0){
        mrS[(w*16 + h*8 + rl)*2+0] = mean;
        mrS[(w*16 + h*8 + rl)*2+1] = rstd;
      }
    }
  }
  __syncthreads();   // scratch reads done before Bp2 staging overwrites [0,32KB)

  // ---- GEMM#2 prologue: stage Bp2[0]->buf0, Bp2[1]->buf1 ----
#pragma unroll
  for (int i=0;i<4;i++)
    gload_lds16(Bp2 + (((i<<2)+w)<<9) + l*8, bsh + (((i<<2)+w)<<9));
#pragma unroll
  for (int i=0;i<4;i++)
    gload_lds16(Bp2 + 8192 + (((i<<2)+w)<<9) + l*8, bsh + 8192 + (((i<<2)+w)<<9));

  // ---- A-build #2: LN_m(p2) from tileA + mrS (all wave-local LDS) ----
  const float mean2 = mrS[(w*16 + lq)*2+0];
  const float rstd2 = mrS[(w*16 + lq)*2+1];
  bf16x8 av2[8];
#pragma unroll
  for (int kk=0;kk<8;kk++){
    const int co = kk*32 + q*8;
    unsigned tb = (unsigned)(lq*512 + kk*64 + q*16);
    bf16x8 u = *(const bf16x8*)(tAw + (tb ^ ((unsigned)(lq&7)<<4)));
    f32x4 ga0 = *(const f32x4*)(g2 + co), ga1 = *(const f32x4*)(g2 + co + 4);
    f32x4 ba0 = *(const f32x4*)(b2 + co), ba1 = *(const f32x4*)(b2 + co + 4);
#pragma unroll
    for (int j=0;j<4;j++) av2[kk][j]   = (__bf16)(((float)u[j]  -mean2)*rstd2*ga0[j] + ba0[j]);
#pragma unroll
    for (int j=0;j<4;j++) av2[kk][4+j] = (__bf16)(((float)u[4+j]-mean2)*rstd2*ga1[j] + ba1[j]);
  }

  __syncthreads();   // drain GEMM#2 prologue

  // ---- GEMM#2: same hardened pipeline vs packed W_mlp ----
#pragma unroll
  for (int ct=0;ct<16;ct++) acc[ct]=zero;
#pragma unroll
  for (int kk=0;kk<8;kk++){
    __builtin_amdgcn_sched_barrier(0);
    if (kk<7) asm volatile("s_waitcnt vmcnt(4)\n\ts_barrier" ::: "memory");
    else      asm volatile("s_waitcnt vmcnt(0)\n\ts_barrier" ::: "memory");
    __builtin_amdgcn_sched_barrier(0);
    if (kk<6){
#pragma unroll
      for (int i=0;i<4;i++)
        gload_lds16(Bp2 + (size_t)(kk+2)*8192 + (((i<<2)+w)<<9) + l*8,
                    bsh + ((kk+2)%3)*8192 + (((i<<2)+w)<<9));
    }
#pragma unroll
    for (int ct=0;ct<16;ct++){
      bf16x8 bfv = *(const bf16x8*)(bsh + (kk%3)*8192 + (((ct<<6)+l)<<3));
      acc[ct] = __builtin_amdgcn_mfma_f32_16x16x32_bf16(av2[kk], bfv, acc[ct], 0,0,0);
    }
  }
  __builtin_amdgcn_sched_barrier(0);
  __syncthreads();   // B reads done; bufs -> f32 scratch again

  // ---- Epilogue #2 (gemmL-style): out = acc + p2(tileA) + bias, f32 coalesced ----
#pragma unroll
  for (int h2=0;h2<2;h2++){
    if (h2) __syncthreads();
#pragma unroll
    for (int ct=0;ct<8;ct++){
      int ctg = h2*8+ct;
#pragma unroll
      for (int rr=0;rr<4;rr++){
        int row = q*4+rr;
        unsigned byte = (unsigned)(row*512 + ct*64 + lq*4);
        *(float*)(myl + (byte ^ ((unsigned)(row&7)<<4))) = acc[ctg][rr];
      }
    }
    __syncthreads();
#pragma unroll
    for (int i=0;i<8;i++){
      int lin = i*64 + l;
      int row = lin>>5, c4 = lin&31;
      unsigned byte = (unsigned)(row*512 + c4*16);
      f32x4 cv = *(f32x4*)(myl + (byte ^ ((unsigned)(row&7)<<4)));
      const size_t grow = (size_t)(1 + rbase + row);
      int col = h2*128 + c4*4;
      unsigned tb = (unsigned)(row*512 + col*2);
      bf16x4 xr = *(const bf16x4*)(tAw + (tb ^ ((unsigned)(row&7)<<4)));
      const float4 bb = *(const float4*)(bias + col);
      *(float4*)(outf + grow*256 + col) =
          make_float4(cv[0]+(float)xr[0]+bb.x, cv[1]+(float)xr[1]+bb.y,
                      cv[2]+(float)xr[2]+bb.z, cv[3]+(float)xr[3]+bb.w);
    }
  }
}

extern "C" void kernel_launch(void* const* d_in, const int* in_sizes, int n_in,
                              void* d_out, int out_size, void* d_ws, size_t ws_size,
                              hipStream_t stream){
  const float* emb    = (const float*)d_in[0];
  const float* ln_t_g = (const float*)d_in[1];
  const float* ln_t_b = (const float*)d_in[2];
  const float* Wq_t   = (const float*)d_in[3];
  const float* Wk_t   = (const float*)d_in[4];
  const float* Wv_t   = (const float*)d_in[5];
  const float* Wt_t   = (const float*)d_in[6];
  const float* ln_s_g = (const float*)d_in[7];
  const float* ln_s_b = (const float*)d_in[8];
  const float* Wq_s   = (const float*)d_in[9];
  const float* Wk_s   = (const float*)d_in[10];
  const float* Wv_s   = (const float*)d_in[11];
  const float* Wt_s   = (const float*)d_in[12];
  const float* ln_m_g = (const float*)d_in[13];
  const float* ln_m_b = (const float*)d_in[14];
  const float* W_mlp  = (const float*)d_in[15];
  const float* b_mlp  = (const float*)d_in[16];
  float* outf = (float*)d_out;

  // ---- d_out overlay: MR0 only (dead before k_gemmFL writes all of d_out) ----
  float*  MR0 = outf + 8388736;              // 131074 f32

  // ---- workspace layout ----
  float* W      = (float*)d_ws;
  float* SUMS   = W;                         // 64
  float* THAT1  = W + 64;                    // 64 (raw, unscaled)
  float* THAT2  = W + 128;                   // 64
  float* Y0F1   = W + 192;                   // 256
  float* Y0F2   = W + 448;                   // 256
  float* TOKAC1 = W + 704;                   // 256
  float* TOKAC2 = W + 960;                   // 256
  float* AW0    = W + 1216;                  // 8192
  float* SPL    = W + 9408;                  // 524288 (phase-2 splane only)
  float* AWSV   = W + 533696;                // 524288
  float* PGRP   = W + 1057984;               // 262144 (ph1 by k_score, ph2 by gemmF1)
  float* MR1    = W + 1320128;               // 131074 (reserve 131104)
  __bf16* BFB   = (__bf16*)(W + 1451232);
  __bf16* PT    = BFB;                       // packed Wt_t fragments (65536)
  __bf16* PS    = BFB + 65536;               // packed Wt_s fragments
  __bf16* PM    = BFB + 131072;              // packed W_mlp fragments
  __bf16* Y0BF1 = BFB + 196608;              // 256
  __bf16* Y0BF2 = BFB + 196864;              // 256
  __bf16* P1B   = BFB + 197120;              // 65537*256 bf16

  k_prep<<<103,256,0,stream>>>(Wq_t,Wk_t,Wv_t,Wq_s,Wk_s,Wv_s,Wt_t,Wt_s,W_mlp,
                               emb, ln_t_g, ln_t_b,
                               SUMS, THAT1, Y0F1, Y0BF1, TOKAC1, PT,PS,PM);

  // ---- phase 1: LN/scores + in-block softmax (k_softmax<1> fused in); pgrp partials out ----
  k_score<<<1024,256,0,stream>>>(emb, ln_t_g, ln_t_b, SUMS, 0, THAT1, AWSV, AW0, PGRP, MR0);
  k_tok1<<<32,256,0,stream>>>(PGRP, AW0, TOKAC1, 0);

  // ---- phase-1 GEMM (p1b bf16 -> WS) + fused phase-2 LN/score epilogue ----
  k_gemmF<1><<<1025,256,0,stream>>>(emb, nullptr, P1B, PT, MR0, ln_t_g, ln_t_b,
                                    Y0BF1, AWSV, AW0, 6, SUMS, 0, Wt_t, Y0F1, TOKAC1,
                                    ln_s_g, ln_s_b, MR1,
                                    THAT2, Y0F2, Y0BF2, TOKAC2, SPL, PGRP);
  k_softmax<16><<<128,256,0,stream>>>(SPL, THAT2, SUMS, 1, AWSV, AW0, 512);
  k_tok1<<<32,256,0,stream>>>(PGRP, AW0, TOKAC2, 4);

  // ---- fused phase-2 GEMM + final GEMM: p1b -> (p2 in LDS) -> f32 out ----
  k_gemmFL<<<1025,256,0,stream>>>(P1B, outf, PS, PM, MR1, ln_s_g, ln_s_b,
                                  Y0BF2, AWSV, AW0, 10, SUMS, 1, Wt_s, Y0F2, TOKAC2,
                                  ln_m_g, ln_m_b, W_mlp, b_mlp);
}